// Round 6
// baseline (188.423 us; speedup 1.0000x reference)
//
#include <hip/hip_runtime.h>

#define N_NODES 100000
#define N_EDGES 640000
#define F 128

typedef __attribute__((ext_vector_type(8))) short short8;
typedef __attribute__((ext_vector_type(4))) float float4v;

// RNE float -> bf16 bits
static __device__ __forceinline__ unsigned short f2bf(float f) {
    unsigned int u = __float_as_uint(f);
    u += 0x7fffu + ((u >> 16) & 1u);
    return (unsigned short)(u >> 16);
}

// ---------------------------------------------------------------------------
// Kernel 0: transpose+convert W1 (fp32 [256][128]) into Wt bf16 [256][128]:
//   Wt[n][k] = W1[(n&128)+k][n&127]
// n<128 rows = A-half (W1[k][n]); n>=128 = B-half. 64 KB, stays L2-hot.
// ---------------------------------------------------------------------------
__global__ __launch_bounds__(256) void prep_wt(
    const float* __restrict__ W1, unsigned short* __restrict__ Wt)
{
    int id = blockIdx.x * 256 + threadIdx.x;       // 0 .. 32767
    int n = id >> 7, k = id & 127;
    float v = W1[((n & 128) + k) * 128 + (n & 127)];
    Wt[id] = f2bf(v);
}

// ---------------------------------------------------------------------------
// Kernel 1: node projections via bf16 MFMA — BARRIER-FREE, NO LDS.
// Operand roles swapped vs rounds 2-5: D[m=wcol][n=node] = Wt · h^T.
//   A-frag (m=l16): Wt[w*64 + p*16 + l16][k-chunk]   (direct, row-major, L2-hot)
//   B-frag (n=l16): bf16(h[node0 + nt*16 + l16][k-chunk]) (contiguous, cvt in reg)
//   C/D: row(quad*4+r)=wcol, col(l16)=node -> lane owns 1 node x 4 consec wcols
//        -> packed 8B stores.
// Wave w covers wcols w*64..w*64+63 (w<2 -> A with b1 bias, w>=2 -> B).
// M=32 nodes/block, 3125 blocks exactly (100000 = 3125*32): no tail guards.
// No __syncthreads anywhere: pure streaming, latency hidden by occupancy.
// ---------------------------------------------------------------------------
__global__ __launch_bounds__(256, 4) void node_proj(
    const float* __restrict__ h, const unsigned short* __restrict__ Wt,
    const float* __restrict__ b1,
    unsigned short* __restrict__ A, unsigned short* __restrict__ B)
{
    const int tid   = threadIdx.x;
    const int lane  = tid & 63;
    const int l16   = lane & 15;
    const int quad  = lane >> 4;
    const int w     = tid >> 6;              // wave id: wcol range w*64..w*64+63
    const int node0 = blockIdx.x * 32;

    float4v acc[4][2];                       // [p = wcol tile][nt = node tile]
#pragma unroll
    for (int p = 0; p < 4; ++p)
#pragma unroll
        for (int nt = 0; nt < 2; ++nt) acc[p][nt] = (float4v){0.f, 0.f, 0.f, 0.f};

    const unsigned short* wbase = Wt + (size_t)(w * 64 + l16) * F;
    const float* hrow0 = h + (size_t)(node0 + l16) * F;       // nt=0 row
    const float* hrow1 = h + (size_t)(node0 + 16 + l16) * F;  // nt=1 row

#pragma unroll
    for (int k0 = 0; k0 < 4; ++k0) {
        const int kb = k0 * 32 + quad * 8;   // float (= bf16) index within row

        // B-frags: h rows -> bf16 (registers only)
        short8 bf[2];
#pragma unroll
        for (int nt = 0; nt < 2; ++nt) {
            const float* hp = (nt == 0 ? hrow0 : hrow1) + kb;
            float4 f0 = *(const float4*)hp;
            float4 f1 = *(const float4*)(hp + 4);
            short8 s;
            s[0] = (short)f2bf(f0.x); s[1] = (short)f2bf(f0.y);
            s[2] = (short)f2bf(f0.z); s[3] = (short)f2bf(f0.w);
            s[4] = (short)f2bf(f1.x); s[5] = (short)f2bf(f1.y);
            s[6] = (short)f2bf(f1.z); s[7] = (short)f2bf(f1.w);
            bf[nt] = s;
        }

        // A-frags from Wt + MFMA
#pragma unroll
        for (int p = 0; p < 4; ++p) {
            short8 af = *(const short8*)(wbase + (size_t)p * 16 * F + kb);
#pragma unroll
            for (int nt = 0; nt < 2; ++nt)
                acc[p][nt] = __builtin_amdgcn_mfma_f32_16x16x32_bf16(
                    af, bf[nt], acc[p][nt], 0, 0, 0);
        }
    }

    // Epilogue: lane holds, per (p,nt): node = node0+nt*16+l16,
    // wcols col..col+3 (regs r=0..3). Pack 4 bf16 -> one 8B store.
    unsigned short* outp = (w < 2) ? A : B;
    const int colbase = (w & 1) * 64;
#pragma unroll
    for (int p = 0; p < 4; ++p) {
        const int col = colbase + p * 16 + quad * 4;
        float4 bv = make_float4(0.f, 0.f, 0.f, 0.f);
        if (w < 2) bv = *(const float4*)(b1 + col);
#pragma unroll
        for (int nt = 0; nt < 2; ++nt) {
            const int node = node0 + nt * 16 + l16;
            ushort4 sv;
            sv.x = f2bf(acc[p][nt][0] + bv.x);
            sv.y = f2bf(acc[p][nt][1] + bv.y);
            sv.z = f2bf(acc[p][nt][2] + bv.z);
            sv.w = f2bf(acc[p][nt][3] + bv.w);
            *(ushort4*)(outp + (size_t)node * F + col) = sv;
        }
    }
}

// ---------------------------------------------------------------------------
// Kernel 2: per-edge score from bf16 A,B. (unchanged from round 5 — best known)
// 8 lanes/edge, 16 channels/lane, 4 edges per group (16 gathers in flight).
// ---------------------------------------------------------------------------
__global__ __launch_bounds__(256) void edge_score(
    const unsigned short* __restrict__ A, const unsigned short* __restrict__ B,
    const int* __restrict__ src, const int* __restrict__ dst,
    const float* __restrict__ W2, const float* __restrict__ b2,
    float* __restrict__ out)
{
    const int tid = threadIdx.x;
    const int sub = tid & 7;                      // lane within edge-group
    const int e0  = blockIdx.x * 128 + (tid >> 3) * 4;   // 4 edges per group
    const int j0  = sub * 16;

    const int4 sv = *(const int4*)(src + e0);
    const int4 dv = *(const int4*)(dst + e0);
    const int s[4] = {sv.x, sv.y, sv.z, sv.w};
    const int d[4] = {dv.x, dv.y, dv.z, dv.w};

    uint4 av0[4], av1[4], bv0[4], bv1[4];
#pragma unroll
    for (int i = 0; i < 4; ++i) {
        const uint4* Ap = (const uint4*)(A + (size_t)s[i] * F + j0);
        const uint4* Bp = (const uint4*)(B + (size_t)d[i] * F + j0);
        av0[i] = Ap[0]; av1[i] = Ap[1];
        bv0[i] = Bp[0]; bv1[i] = Bp[1];
    }

    const float4* Wp = (const float4*)(W2 + j0);
    const float4 w0 = Wp[0], w1 = Wp[1], w2 = Wp[2], w3 = Wp[3];
    const float bias = b2[0];

#define TERM(UA, UB, WL, WH)                                                   \
    {                                                                          \
        float fa0 = __uint_as_float((UA) << 16);                               \
        float fa1 = __uint_as_float((UA) & 0xFFFF0000u);                       \
        float fb0 = __uint_as_float((UB) << 16);                               \
        float fb1 = __uint_as_float((UB) & 0xFFFF0000u);                       \
        sacc = fmaf(fmaxf(fa0 + fb0, 0.f), (WL), sacc);                        \
        sacc = fmaf(fmaxf(fa1 + fb1, 0.f), (WH), sacc);                        \
    }
#pragma unroll
    for (int i = 0; i < 4; ++i) {
        float sacc = 0.f;
        TERM(av0[i].x, bv0[i].x, w0.x, w0.y)
        TERM(av0[i].y, bv0[i].y, w0.z, w0.w)
        TERM(av0[i].z, bv0[i].z, w1.x, w1.y)
        TERM(av0[i].w, bv0[i].w, w1.z, w1.w)
        TERM(av1[i].x, bv1[i].x, w2.x, w2.y)
        TERM(av1[i].y, bv1[i].y, w2.z, w2.w)
        TERM(av1[i].z, bv1[i].z, w3.x, w3.y)
        TERM(av1[i].w, bv1[i].w, w3.z, w3.w)
        sacc += __shfl_xor(sacc, 1);
        sacc += __shfl_xor(sacc, 2);
        sacc += __shfl_xor(sacc, 4);
        if (sub == 0) out[e0 + i] = sacc + bias;
    }
#undef TERM
}

extern "C" void kernel_launch(void* const* d_in, const int* in_sizes, int n_in,
                              void* d_out, int out_size, void* d_ws, size_t ws_size,
                              hipStream_t stream) {
    const float* h   = (const float*)d_in[0];
    const int*   src = (const int*)d_in[1];
    const int*   dst = (const int*)d_in[2];
    const float* W1  = (const float*)d_in[3];
    const float* b1  = (const float*)d_in[4];
    const float* W2  = (const float*)d_in[5];
    const float* b2  = (const float*)d_in[6];
    float* out = (float*)d_out;

    // workspace layout (bf16): Wt[256][128] | A[100000][128] | B[100000][128]
    unsigned short* Wt = (unsigned short*)d_ws;
    unsigned short* A  = Wt + 256 * 128;
    unsigned short* B  = A + (size_t)N_NODES * F;

    prep_wt<<<128, 256, 0, stream>>>(W1, Wt);
    node_proj<<<N_NODES / 32, 256, 0, stream>>>(h, Wt, b1, A, B);
    edge_score<<<N_EDGES / 128, 256, 0, stream>>>(A, B, src, dst, W2, b2, out);
}

// Round 7
// 166.136 us; speedup vs baseline: 1.1341x; 1.1341x over previous
//
#include <hip/hip_runtime.h>

#define N_NODES 100000
#define N_EDGES 640000
#define F 128
#define NT 6250          // 16-node tiles (100000 = 6250*16 exactly)

typedef __attribute__((ext_vector_type(8))) short short8;
typedef __attribute__((ext_vector_type(4))) float float4v;

// RNE float -> bf16 bits
static __device__ __forceinline__ unsigned short f2bf(float f) {
    unsigned int u = __float_as_uint(f);
    u += 0x7fffu + ((u >> 16) & 1u);
    return (unsigned short)(u >> 16);
}

// ---------------------------------------------------------------------------
// Kernel 0: transpose+convert W1 (fp32 [256][128]) into Wt bf16 [256][128]:
//   Wt[n][k] = W1[(n&128)+k][n&127]
// ---------------------------------------------------------------------------
__global__ __launch_bounds__(256) void prep_wt(
    const float* __restrict__ W1, unsigned short* __restrict__ Wt)
{
    int id = blockIdx.x * 256 + threadIdx.x;       // 0 .. 32767
    int n = id >> 7, k = id & 127;
    float v = W1[((n & 128) + k) * 128 + (n & 127)];
    Wt[id] = f2bf(v);
}

// ---------------------------------------------------------------------------
// Kernel 1: node projections — wave-private software pipeline.
// SESSION LAW (r4/r5-vs-r2/r6 evidence): all GLOBAL loads lane-contiguous;
// lane-transposes go through LDS.
//   grid = (256, 2); y selects W half (y=0 -> A + b1 bias, y=1 -> B).
//   Per block: stage Wt half (128x128 bf16) into LDS once; ONE barrier.
//   Per wave: loop over 16-node tiles (t += 1024), double-buffered private
//   h stage in LDS; prefetch tile t+1 h into regs (coalesced float4) while
//   computing tile t. D[m=wcol][n=node] = Wt·h^T via mfma_16x16x32_bf16:
//     A-frag = w_lds row (m=l16), B-frag = h_lds row (n=l16),
//     C/D: wcol = quad*4+reg (per 16-col tile), node = l16.
//   Epilogue: packed 8B ushort4 stores.
// LDS: 34.8 KB (W) + 4 waves x 2 bufs x 4.35 KB (h) = 69.6 KB -> 2 blocks/CU.
// Stride 136 shorts: 16B-aligned, bank-balanced (8 word-hits/bank = floor).
// ---------------------------------------------------------------------------
__global__ __launch_bounds__(256, 4) void node_proj(
    const float* __restrict__ h, const unsigned short* __restrict__ Wt,
    const float* __restrict__ b1,
    unsigned short* __restrict__ A, unsigned short* __restrict__ B)
{
    __shared__ unsigned short w_lds[128 * 136];          // 34.8 KB
    __shared__ unsigned short h_lds[4][2][16 * 136];     // 34.8 KB

    const int tid  = threadIdx.x;
    const int lane = tid & 63;
    const int l16  = lane & 15;
    const int quad = lane >> 4;
    const int w    = tid >> 6;
    const int y    = blockIdx.y;

    // ---- stage Wt half into LDS, fully coalesced (uint4 = 8 bf16) ----
#pragma unroll
    for (int i = 0; i < 8; ++i) {
        int c = i * 256 + tid;            // uint4 chunk id, 0..2047
        int r = c >> 4, cc = c & 15;      // 16 chunks per 128-short row
        uint4 v = *(const uint4*)(Wt + (size_t)(y * 128 + r) * F + cc * 8);
        *(uint4*)&w_lds[r * 136 + cc * 8] = v;
    }
    __syncthreads();                      // the ONLY barrier

    unsigned short* hb0 = &h_lds[w][0][0];
    unsigned short* hb1 = &h_lds[w][1][0];
    unsigned short* outp = (y == 0) ? A : B;

    // lane-constant staging coords: float4 f = i*64+lane; row=f>>5, c4=f&31
    int srow[8], sc4[8];
#pragma unroll
    for (int i = 0; i < 8; ++i) { int f = i * 64 + lane; srow[i] = f >> 5; sc4[i] = f & 31; }

#define LOADH(PF, T)                                                           \
    _Pragma("unroll") for (int i = 0; i < 8; ++i)                              \
        PF[i] = *(const float4*)(h + ((size_t)(T) * 16 + srow[i]) * F + sc4[i] * 4);

#define CVTWRITE(PF, DST)                                                      \
    _Pragma("unroll") for (int i = 0; i < 8; ++i) {                            \
        uint2 p;                                                               \
        p.x = (unsigned)f2bf(PF[i].x) | ((unsigned)f2bf(PF[i].y) << 16);       \
        p.y = (unsigned)f2bf(PF[i].z) | ((unsigned)f2bf(PF[i].w) << 16);       \
        *(uint2*)&(DST)[srow[i] * 136 + sc4[i] * 4] = p;                       \
    }

    int t = blockIdx.x * 4 + w;           // 1024 wave-slots per y-half
    bool act = (t < NT);
    float4 pf[8];
    if (act) { LOADH(pf, t); CVTWRITE(pf, hb0); }

    int buf = 0;
    while (act) {
        const int tn = t + 1024;
        const bool actn = (tn < NT);
        if (actn) LOADH(pf, tn);          // prefetch next tile (global, coalesced)

        // ---- compute tile t from private LDS buffer ----
        unsigned short* hb = buf ? hb1 : hb0;
        float4v acc[8];
#pragma unroll
        for (int mt = 0; mt < 8; ++mt) acc[mt] = (float4v){0.f, 0.f, 0.f, 0.f};
#pragma unroll
        for (int k0 = 0; k0 < 4; ++k0) {
            const int kb = k0 * 32 + quad * 8;
            short8 bf = *(const short8*)&hb[l16 * 136 + kb];
#pragma unroll
            for (int mt = 0; mt < 8; ++mt) {
                short8 af = *(const short8*)&w_lds[(mt * 16 + l16) * 136 + kb];
                acc[mt] = __builtin_amdgcn_mfma_f32_16x16x32_bf16(af, bf, acc[mt], 0, 0, 0);
            }
        }

        // ---- stage next tile into other buffer (vmcnt wait lands here) ----
        if (actn) CVTWRITE(pf, buf ? hb0 : hb1);

        // ---- epilogue: node = t*16 + l16, cols mt*16+quad*4 .. +3 ----
        {
            const size_t nodeoff = ((size_t)t * 16 + l16) * F;
#pragma unroll
            for (int mt = 0; mt < 8; ++mt) {
                const int col = mt * 16 + quad * 4;
                float4 bv = make_float4(0.f, 0.f, 0.f, 0.f);
                if (y == 0) bv = *(const float4*)(b1 + col);
                ushort4 sv;
                sv.x = f2bf(acc[mt][0] + bv.x);
                sv.y = f2bf(acc[mt][1] + bv.y);
                sv.z = f2bf(acc[mt][2] + bv.z);
                sv.w = f2bf(acc[mt][3] + bv.w);
                *(ushort4*)(outp + nodeoff + col) = sv;
            }
        }
        buf ^= 1; t = tn; act = actn;
    }
#undef LOADH
#undef CVTWRITE
}

// ---------------------------------------------------------------------------
// Kernel 2: per-edge score from bf16 A,B. (round-5 best: 8 lanes/edge,
// 16 channels/lane, 4 edges per group -> 16 gathers in flight)
// ---------------------------------------------------------------------------
__global__ __launch_bounds__(256) void edge_score(
    const unsigned short* __restrict__ A, const unsigned short* __restrict__ B,
    const int* __restrict__ src, const int* __restrict__ dst,
    const float* __restrict__ W2, const float* __restrict__ b2,
    float* __restrict__ out)
{
    const int tid = threadIdx.x;
    const int sub = tid & 7;
    const int e0  = blockIdx.x * 128 + (tid >> 3) * 4;
    const int j0  = sub * 16;

    const int4 sv = *(const int4*)(src + e0);
    const int4 dv = *(const int4*)(dst + e0);
    const int s[4] = {sv.x, sv.y, sv.z, sv.w};
    const int d[4] = {dv.x, dv.y, dv.z, dv.w};

    uint4 av0[4], av1[4], bv0[4], bv1[4];
#pragma unroll
    for (int i = 0; i < 4; ++i) {
        const uint4* Ap = (const uint4*)(A + (size_t)s[i] * F + j0);
        const uint4* Bp = (const uint4*)(B + (size_t)d[i] * F + j0);
        av0[i] = Ap[0]; av1[i] = Ap[1];
        bv0[i] = Bp[0]; bv1[i] = Bp[1];
    }

    const float4* Wp = (const float4*)(W2 + j0);
    const float4 w0 = Wp[0], w1 = Wp[1], w2 = Wp[2], w3 = Wp[3];
    const float bias = b2[0];

#define TERM(UA, UB, WL, WH)                                                   \
    {                                                                          \
        float fa0 = __uint_as_float((UA) << 16);                               \
        float fa1 = __uint_as_float((UA) & 0xFFFF0000u);                       \
        float fb0 = __uint_as_float((UB) << 16);                               \
        float fb1 = __uint_as_float((UB) & 0xFFFF0000u);                       \
        sacc = fmaf(fmaxf(fa0 + fb0, 0.f), (WL), sacc);                        \
        sacc = fmaf(fmaxf(fa1 + fb1, 0.f), (WH), sacc);                        \
    }
#pragma unroll
    for (int i = 0; i < 4; ++i) {
        float sacc = 0.f;
        TERM(av0[i].x, bv0[i].x, w0.x, w0.y)
        TERM(av0[i].y, bv0[i].y, w0.z, w0.w)
        TERM(av0[i].z, bv0[i].z, w1.x, w1.y)
        TERM(av0[i].w, bv0[i].w, w1.z, w1.w)
        TERM(av1[i].x, bv1[i].x, w2.x, w2.y)
        TERM(av1[i].y, bv1[i].y, w2.z, w2.w)
        TERM(av1[i].z, bv1[i].z, w3.x, w3.y)
        TERM(av1[i].w, bv1[i].w, w3.z, w3.w)
        sacc += __shfl_xor(sacc, 1);
        sacc += __shfl_xor(sacc, 2);
        sacc += __shfl_xor(sacc, 4);
        if (sub == 0) out[e0 + i] = sacc + bias;
    }
#undef TERM
}

extern "C" void kernel_launch(void* const* d_in, const int* in_sizes, int n_in,
                              void* d_out, int out_size, void* d_ws, size_t ws_size,
                              hipStream_t stream) {
    const float* h   = (const float*)d_in[0];
    const int*   src = (const int*)d_in[1];
    const int*   dst = (const int*)d_in[2];
    const float* W1  = (const float*)d_in[3];
    const float* b1  = (const float*)d_in[4];
    const float* W2  = (const float*)d_in[5];
    const float* b2  = (const float*)d_in[6];
    float* out = (float*)d_out;

    // workspace layout (bf16): Wt[256][128] | A[100000][128] | B[100000][128]
    unsigned short* Wt = (unsigned short*)d_ws;
    unsigned short* A  = Wt + 256 * 128;
    unsigned short* B  = A + (size_t)N_NODES * F;

    prep_wt<<<128, 256, 0, stream>>>(W1, Wt);
    node_proj<<<dim3(256, 2), 256, 0, stream>>>(h, Wt, b1, A, B);
    edge_score<<<N_EDGES / 128, 256, 0, stream>>>(A, B, src, dst, W2, b2, out);
}